// Round 5
// baseline (216.723 us; speedup 1.0000x reference)
//
#include <hip/hip_runtime.h>

#define NN 100
#define CC 256
#define NKK 103
#define LDPW 136   // PW stride (bf16): 272 B rows, 16B-aligned frags, 2-way bank alias (free)
#define OTS 260    // out-transpose stride (f32): 1040 B rows, 16B-aligned
#define LHALO 34   // halo stride (f32): 136 B rows -> bank-staggered

typedef __bf16 bf16;
typedef __bf16 bf16x8 __attribute__((ext_vector_type(8)));
typedef float f32x4 __attribute__((ext_vector_type(4)));

// kernel0: W (f32 [256][103]) -> Wt (bf16 [103][256]) in workspace.
__global__ void wl_transpose(const float* __restrict__ W, bf16* __restrict__ Wt)
{
    int idx = blockIdx.x * 256 + threadIdx.x;
    if (idx < NKK * CC) {
        int ka = idx >> 8;      // /256
        int k  = idx & 255;
        Wt[ka * CC + k] = (bf16)W[k * NKK + ka];
    }
}

// 256-thread / 4-wave blocks, one batch each, 512 blocks, 256 unified regs/wave.
// Round-5 focus: memory-level parallelism.  Block latency == dispatch latency
// (all 512 blocks resident) and rounds 0-4 were flat at ~180k cycles/block vs
// ~5k cycles of compute -> dependent-chain stalls dominate.  Fixes:
//  * phase A: preload ALL q frags per tile (16 loads in flight, no per-kc WAR);
//    J-outer loop so one batch of 8 Wt loads feeds 16 MFMAs (2 row-tiles share B)
//  * phase B: explicit xn double-buffer across ks (kills the xv WAR serialization)
//  * conv halo: staged into LDS pre-barrier; NO divergent global loads in conv
//
// SMEM layout:
// [    0, 27200)  PW   bf16 [100][136]
// [27200, 28400)  DW   f32  [100][3]
// [28400, 31600)  RP   f32  [4][100][2]
// [31600, 45200)  HALO f32  [100][34]  (k even: col 16*(k/2)-1 ; k odd: col 16*(k+1)/2)
// [52000, 52800)  RS   f32  [100][2]           (outside OT alias range)
// phase D: OT f32 [50][260] aliases [0, 52000)  (PW/DW/RP/HALO dead by then)
__global__ __launch_bounds__(256, 2)
void dysepconv_fused(const float* __restrict__ query,
                     const float* __restrict__ value,
                     const bf16*  __restrict__ Wt,
                     const float* __restrict__ bwl,
                     const float* __restrict__ gamma,
                     const float* __restrict__ beta,
                     float* __restrict__ out)
{
    __shared__ __align__(16) char SMEM[52800];
    bf16*  PW = (bf16*)SMEM;
    float (*DW)[3]      = (float(*)[3])(SMEM + 27200);
    float (*RP)[NN][2]  = (float(*)[NN][2])(SMEM + 28400);
    float (*HALO)[LHALO]= (float(*)[LHALO])(SMEM + 31600);
    float (*RS)[2]      = (float(*)[2])(SMEM + 52000);
    float* OT = (float*)SMEM;

    const int t    = threadIdx.x;
    const int w    = t >> 6;          // wave 0..3
    const int lane = t & 63;
    const int ln16 = lane & 15;
    const int g    = lane >> 4;
    const int hi8  = g * 8;
    const int b    = blockIdx.x;
    const int cb0  = w * 16 + ln16;   // channel base 0..63; lane owns cb0 + 64*s, s=0..3

    const float* qb = query + (size_t)b * NN * CC;
    const float* vb = value + (size_t)b * NN * CC;

    // ---------------- Phase A: dy = q @ W + bias (no LDS, no barriers) ----------------
    // wave w owns dy row-tiles {w, w+4}; wave 3 has only tile 3.
    const int nt = (w < 3) ? 2 : 1;

    f32x4 acc1[2][7];
    #pragma unroll
    for (int u = 0; u < 2; ++u)
        #pragma unroll
        for (int J = 0; J < 7; ++J) acc1[u][J] = (f32x4){0.f, 0.f, 0.f, 0.f};

    // preload ALL q fragments for both tiles: 16 strided 16B loads in flight/tile
    bf16x8 qfr[2][8];                 // f = kc*2+s -> cols kc*64 + s*32 + hi8 .. +7
    #pragma unroll
    for (int u = 0; u < 2; ++u) {
        if (u < nt) {
            const int tile = w + u * 4;
            const int qrow = (tile * 16 + ln16 < NN) ? (tile * 16 + ln16) : (NN - 1);
            const float* qr = qb + qrow * CC;
            #pragma unroll
            for (int f = 0; f < 8; ++f) {
                const int col = (f >> 1) * 64 + (f & 1) * 32 + hi8;
                f32x4 a0 = *(const f32x4*)(qr + col);
                f32x4 a1 = *(const f32x4*)(qr + col + 4);
                #pragma unroll
                for (int i = 0; i < 4; ++i) { qfr[u][f][i] = (bf16)a0[i]; qfr[u][f][i + 4] = (bf16)a1[i]; }
            }
        }
    }

    // J-outer: one batch of 8 Wt fragment loads feeds up to 16 MFMAs
    #pragma unroll
    for (int J = 0; J < 7; ++J) {
        const int rB = (J * 16 + ln16 < NKK) ? (J * 16 + ln16) : (NKK - 1); // clamp: cols>=103 discarded
        const bf16* wr = Wt + rB * CC;
        bf16x8 bv[8];
        #pragma unroll
        for (int f = 0; f < 8; ++f)
            bv[f] = *(const bf16x8*)(wr + (f >> 1) * 64 + (f & 1) * 32 + hi8);
        #pragma unroll
        for (int u = 0; u < 2; ++u) {
            if (u < nt) {
                #pragma unroll
                for (int f = 0; f < 8; ++f)
                    acc1[u][J] = __builtin_amdgcn_mfma_f32_16x16x32_bf16(qfr[u][f], bv[f], acc1[u][J], 0, 0, 0);
            }
        }
    }

    // ---- epilogue A (overlapped latency: halo staging + ks0 prefetch issue early) ----
    // conv halo table: k even -> col 16*(k/2)-1 (left), k odd -> col 16*(k+1)/2 (right)
    for (int i = t; i < NN * 32; i += 256) {
        int m = i >> 5, k = i & 31;
        int col = (k & 1) ? (16 * ((k + 1) >> 1)) : (16 * (k >> 1) - 1);
        HALO[m][k] = (col >= 0 && col < CC) ? vb[m * CC + col] : 0.f;
    }
    // zero PW k-pad cols (must be exact 0)
    for (int i = t; i < NN * 28; i += 256) {
        int r = i / 28, m = 100 + (i - (i / 28) * 28);
        PW[r * LDPW + m] = (bf16)0.f;
    }
    // prefetch value loads for ks=0
    float xv[4][8];
    #pragma unroll
    for (int s = 0; s < 4; ++s)
        #pragma unroll
        for (int j = 0; j < 8; ++j) {
            int m = hi8 + j;                   // ks=0: m < 32 < NN always
            xv[s][j] = vb[m * CC + cb0 + 64 * s];
        }
    // write pw (bf16) / dw (fp32).  D: row = tile*16+g*4+r, col = J*16+ln16
    #pragma unroll
    for (int u = 0; u < 2; ++u) {
        if (u < nt) {
            #pragma unroll
            for (int J = 0; J < 7; ++J) {
                int kap = J * 16 + ln16;
                float bw = (kap < NKK) ? bwl[kap] : 0.f;
                #pragma unroll
                for (int r = 0; r < 4; ++r) {
                    int n = (w + u * 4) * 16 + g * 4 + r;
                    if (n < NN && kap < NKK) {
                        float v = acc1[u][J][r] + bw;
                        if (kap < 3) DW[n][kap] = v;
                        else         PW[n * LDPW + (kap - 3)] = (bf16)v;
                    }
                }
            }
        }
    }
    __syncthreads();   // PW/DW/HALO visible

    // ---------------- Phase B/C: conv (double-buffered loads, LDS halo) + GEMM2 ----------------
    f32x4 acc2[4][7];
    #pragma unroll
    for (int s = 0; s < 4; ++s)
        #pragma unroll
        for (int I = 0; I < 7; ++I) acc2[s][I] = (f32x4){0.f, 0.f, 0.f, 0.f};

    #pragma unroll
    for (int ks = 0; ks < 4; ++ks) {
        float xn[4][8];
        if (ks < 3) {   // issue next-ks loads BEFORE the conv chain (fresh regs: no WAR)
            #pragma unroll
            for (int s = 0; s < 4; ++s)
                #pragma unroll
                for (int j = 0; j < 8; ++j) {
                    int m = (ks + 1) * 32 + hi8 + j;
                    bool mv = (m < NN);
                    xn[s][j] = mv ? vb[m * CC + cb0 + 64 * s] : 0.f;
                }
        }
        bf16x8 dv[4];
        #pragma unroll
        for (int j = 0; j < 8; ++j) {
            int  m  = ks * 32 + hi8 + j;
            bool mv = (m < NN);
            int  mc = mv ? m : (NN - 1);
            float w0 = DW[mc][0], w1 = DW[mc][1], w2 = DW[mc][2];   // row-only: shared by 4 segs
            #pragma unroll
            for (int s = 0; s < 4; ++s) {
                float x0 = xv[s][j];
                float xm = __shfl(x0, (lane - 1) & 63);
                float xp = __shfl(x0, (lane + 1) & 63);
                const int i0 = w + 4 * s;                 // segment index, c0 = 16*i0
                if (ln16 == 0)  xm = HALO[mc][2 * i0];
                if (ln16 == 15) xp = HALO[mc][2 * i0 + 1];
                float d = w0 * xm + w1 * x0 + w2 * xp;
                dv[s][j] = (bf16)(mv ? fmaxf(d, 0.f) : 0.f);
            }
        }
        #pragma unroll
        for (int I = 0; I < 7; ++I) {
            int row = I * 16 + ln16;
            row = (row < NN) ? row : (NN - 1);   // PW has 100 rows; clamped rows discarded
            bf16x8 af = *(const bf16x8*)&PW[row * LDPW + ks * 32 + hi8];   // 1 read feeds 4 MFMAs
            #pragma unroll
            for (int s = 0; s < 4; ++s)
                acc2[s][I] = __builtin_amdgcn_mfma_f32_16x16x32_bf16(af, dv[s], acc2[s][I], 0, 0, 0);
        }
        if (ks < 3) {
            #pragma unroll
            for (int s = 0; s < 4; ++s)
                #pragma unroll
                for (int j = 0; j < 8; ++j) xv[s][j] = xn[s][j];
        }
    }

    // LN affine params (L2-hot)
    float gm[4], bt[4];
    #pragma unroll
    for (int s = 0; s < 4; ++s) { gm[s] = gamma[cb0 + 64 * s]; bt[s] = beta[cb0 + 64 * s]; }

    // ---------------- Phase D: LayerNorm ----------------
    #pragma unroll
    for (int I = 0; I < 7; ++I) {
        #pragma unroll
        for (int r = 0; r < 4; ++r) {
            float s1 = 0.f, s2 = 0.f;
            #pragma unroll
            for (int s = 0; s < 4; ++s) {
                float a = acc2[s][I][r];
                s1 += a; s2 += a * a;
            }
            #pragma unroll
            for (int mk = 1; mk < 16; mk <<= 1) {
                s1 += __shfl_xor(s1, mk);
                s2 += __shfl_xor(s2, mk);
            }
            int n = I * 16 + g * 4 + r;
            if (ln16 == 0 && n < NN) {
                RP[w][n][0] = s1;
                RP[w][n][1] = s2;
            }
        }
    }
    __syncthreads();   // RP visible; PW/DW/HALO reads all complete
    if (t < NN) {
        float S1 = 0.f, S2 = 0.f;
        #pragma unroll
        for (int wi = 0; wi < 4; ++wi) { S1 += RP[wi][t][0]; S2 += RP[wi][t][1]; }
        float mu  = S1 * (1.f / 256.f);
        float var = S2 * (1.f / 256.f) - mu * mu;
        RS[t][0] = mu;
        RS[t][1] = rsqrtf(fmaxf(var, 0.f) + 1e-5f);
    }
    __syncthreads();   // RS visible; RP dead -> OT alias safe

    // normalize + transpose through LDS in 2 chunks of 50 rows
    float* ob = out + (size_t)b * NN * CC;
    #pragma unroll
    for (int h = 0; h < 2; ++h) {
        const int n0 = h * 50;
        #pragma unroll
        for (int I = 0; I < 7; ++I) {
            #pragma unroll
            for (int r = 0; r < 4; ++r) {
                int n = I * 16 + g * 4 + r;
                if (n >= n0 && n < n0 + 50 && n < NN) {
                    float mu = RS[n][0], rs = RS[n][1];
                    int rt = n - n0;
                    #pragma unroll
                    for (int s = 0; s < 4; ++s)
                        OT[rt * OTS + cb0 + 64 * s] = (acc2[s][I][r] - mu) * rs * gm[s] + bt[s];
                }
            }
        }
        __syncthreads();
        #pragma unroll
        for (int p = 0; p < 13; ++p) {
            int idx = p * 256 + t;              // 50 rows x 64 f32x4 = 3200
            if (idx < 50 * 64) {
                int row = idx >> 6, c4 = (idx & 63) << 2;
                *(f32x4*)(ob + (size_t)(n0 + row) * CC + c4) = *(const f32x4*)&OT[row * OTS + c4];
            }
        }
        if (h == 0) __syncthreads();
    }
}

extern "C" void kernel_launch(void* const* d_in, const int* in_sizes, int n_in,
                              void* d_out, int out_size, void* d_ws, size_t ws_size,
                              hipStream_t stream) {
    const float* query = (const float*)d_in[0];
    const float* value = (const float*)d_in[1];
    const float* W     = (const float*)d_in[2];
    const float* bwl   = (const float*)d_in[3];
    const float* gamma = (const float*)d_in[4];
    const float* beta  = (const float*)d_in[5];
    bf16* Wt = (bf16*)d_ws;   // 103*256*2 = 52736 B

    wl_transpose<<<dim3((NKK * CC + 255) / 256), dim3(256), 0, stream>>>(W, Wt);
    dysepconv_fused<<<dim3(512), dim3(256), 0, stream>>>(query, value, Wt, bwl, gamma, beta, (float*)d_out);
}

// Round 9
// 186.259 us; speedup vs baseline: 1.1636x; 1.1636x over previous
//
#include <hip/hip_runtime.h>

#define NN 100
#define CC 256
#define NKK 103
#define LDT 136    // depthT stride (bf16): 272 B rows -> lanes hit banks i*4%32, 2-way alias (free)
                   // NOTE: must be >= 128 (padded contraction range) -- LDT=104 was the round-6 bug
#define OTS 264    // out-transpose stride (f32): 1056 B rows, 16B-aligned, 2-way banks

typedef __bf16 bf16;
typedef __bf16 bf16x8 __attribute__((ext_vector_type(8)));
typedef float f32x4 __attribute__((ext_vector_type(4)));

// Per-batch scratch carved from the head of the out buffer (f32 units, 25600/batch):
//   [    0, 6400)  pw  bf16 [100][128]   (cols 100..127 uninitialized -> masked in k2)
//   [ 6400, 6800)  dw  f32  [100][4]     (col 3 unused)
// Safe: kernel-2 block b reads ONLY batch b's scratch, all before writing out[b]
// (intra-block ordering via barriers); no cross-block aliasing. Poison-safe:
// every scratch word k2 reads is either written by gemm1 or masked in-register.

// kernel0: W (f32 [256][103]) -> Wt (bf16 [103][256]) in workspace.
__global__ void wl_transpose(const float* __restrict__ W, bf16* __restrict__ Wt)
{
    int idx = blockIdx.x * 256 + threadIdx.x;
    if (idx < NKK * CC) {
        int ka = idx >> 8;      // /256
        int k  = idx & 255;
        Wt[ka * CC + k] = (bf16)W[k * NKK + ka];
    }
}

// kernel1: dy = q@W + bias as a flat GEMM [51200][256] x [256][103].
// 800 blocks x 256 thr, wave owns a 16-row tile x all 103 cols. No LDS, no
// barriers, ~100 live regs @ 128 cap -> no spills, 16 waves/CU.
__global__ __launch_bounds__(256, 4)
void gemm1(const float* __restrict__ query, const bf16* __restrict__ Wt,
           const float* __restrict__ bwl, float* __restrict__ out)
{
    const int t    = threadIdx.x;
    const int w    = t >> 6;
    const int lane = t & 63;
    const int ln16 = lane & 15;
    const int g    = lane >> 4;
    const int hi8  = g * 8;
    const int R0   = blockIdx.x * 64 + w * 16;     // wave's flat row tile (always < 51200)

    // A fragments: row R0+ln16, all 256 k (8 frags; g-groups tile the row)
    const float* qr = query + (size_t)(R0 + ln16) * CC;
    bf16x8 qfr[8];
    #pragma unroll
    for (int f = 0; f < 8; ++f) {
        const int col = f * 32 + hi8;
        f32x4 a0 = *(const f32x4*)(qr + col);
        f32x4 a1 = *(const f32x4*)(qr + col + 4);
        #pragma unroll
        for (int i = 0; i < 4; ++i) { qfr[f][i] = (bf16)a0[i]; qfr[f][i + 4] = (bf16)a1[i]; }
    }

    f32x4 acc[7];
    #pragma unroll
    for (int J = 0; J < 7; ++J) acc[J] = (f32x4){0.f, 0.f, 0.f, 0.f};

    #pragma unroll
    for (int J = 0; J < 7; ++J) {
        const int rB = (J * 16 + ln16 < NKK) ? (J * 16 + ln16) : (NKK - 1); // cols>=103 discarded
        const bf16* wr = Wt + rB * CC;
        #pragma unroll
        for (int f = 0; f < 8; ++f) {
            bf16x8 bv = *(const bf16x8*)(wr + f * 32 + hi8);
            acc[J] = __builtin_amdgcn_mfma_f32_16x16x32_bf16(qfr[f], bv, acc[J], 0, 0, 0);
        }
    }

    // epilogue: decompose flat rows once (4 divs), then scatter pw/dw
    int bb[4], nr[4];
    #pragma unroll
    for (int r = 0; r < 4; ++r) {
        int nf = R0 + g * 4 + r;
        bb[r] = nf / 100;                 // compiler magic-mul
        nr[r] = nf - bb[r] * 100;
    }
    #pragma unroll
    for (int J = 0; J < 7; ++J) {
        int kap = J * 16 + ln16;
        float bw = (kap < NKK) ? bwl[kap] : 0.f;
        #pragma unroll
        for (int r = 0; r < 4; ++r) {
            float v = acc[J][r] + bw;
            float* base = out + (size_t)bb[r] * 25600;
            if (kap >= 3 && kap < NKK)
                ((bf16*)base)[nr[r] * 128 + (kap - 3)] = (bf16)v;   // pw
            else if (kap < 3)
                base[6400 + nr[r] * 4 + kap] = v;                   // dw
        }
    }
}

// kernel2: conv -> depthT(LDS) -> GEMM2 -> in-wave LN -> coalesced store.
// 512 blocks x 512 thr (8 waves). acc = 64 f32/thread only; ~125 live @ 128 cap.
// LDS 71232 B -> 2 blocks/CU -> 16 waves/CU (4/SIMD): real TLP for latency hiding.
// SMEM: [0,69632) depthT bf16 [256][136] ; [69632,71232) dw f32 [100][4]
//       phase-store: OT f32 [64][264] (67584 B) aliases everything (depthT/dw dead)
__global__ __launch_bounds__(512, 4)
void conv_gemm2_ln(const float* __restrict__ value,
                   const float* __restrict__ gamma,
                   const float* __restrict__ beta,
                   float* __restrict__ out)
{
    __shared__ __align__(16) char SMEM[71232];
    bf16* depthT = (bf16*)SMEM;                       // [256][LDT]
    float (*DWs)[4] = (float(*)[4])(SMEM + 69632);    // [100][4]
    float* OT = (float*)SMEM;                         // [64][OTS]

    const int t    = threadIdx.x;
    const int w    = t >> 6;          // wave 0..7
    const int lane = t & 63;
    const int ln16 = lane & 15;
    const int g    = lane >> 4;
    const int hi8  = g * 8;
    const int b    = blockIdx.x;
    const int cb   = w * 16 + ln16;   // channel base 0..127; lane owns cb + 128*s

    float* ob = out + (size_t)b * 25600;
    const bf16*  pwb = (const bf16*)ob;               // [100][128]
    const float* vb  = value + (size_t)b * NN * CC;

    // stage dw -> LDS; prefetch ks=0 value (m<32 always valid)
    if (t < 400) ((float*)DWs)[t] = ob[6400 + t];
    float xv[2][8];
    #pragma unroll
    for (int s = 0; s < 2; ++s)
        #pragma unroll
        for (int j = 0; j < 8; ++j)
            xv[s][j] = vb[(hi8 + j) * CC + cb + 128 * s];
    __syncthreads();   // DWs visible

    // ---- conv: depth[m][c] = relu(dw0*v[m][c-1]+dw1*v[m][c]+dw2*v[m][c+1]) ----
    // stored transposed: depthT[c][m], zero for m in [100,128); [128,136) pad never read
    #pragma unroll
    for (int ks = 0; ks < 4; ++ks) {
        if (ks) {
            #pragma unroll
            for (int s = 0; s < 2; ++s)
                #pragma unroll
                for (int j = 0; j < 8; ++j) {
                    int m = ks * 32 + hi8 + j;
                    xv[s][j] = (m < NN) ? vb[m * CC + cb + 128 * s] : 0.f;
                }
        }
        bf16x8 dv[2];
        #pragma unroll
        for (int j = 0; j < 8; ++j) {
            int  m  = ks * 32 + hi8 + j;
            bool mv = (m < NN);
            int  mc = mv ? m : (NN - 1);
            float w0 = DWs[mc][0], w1 = DWs[mc][1], w2 = DWs[mc][2];
            #pragma unroll
            for (int s = 0; s < 2; ++s) {
                int c = cb + 128 * s;
                float x0 = xv[s][j];
                float xm = __shfl(x0, (lane - 1) & 63);
                float xp = __shfl(x0, (lane + 1) & 63);
                if (ln16 == 0)  xm = (mv && c > 0)      ? vb[m * CC + c - 1] : 0.f;
                if (ln16 == 15) xp = (mv && c + 1 < CC) ? vb[m * CC + c + 1] : 0.f;
                float d = w0 * xm + w1 * x0 + w2 * xp;
                dv[s][j] = (bf16)(mv ? fmaxf(d, 0.f) : 0.f);
            }
        }
        #pragma unroll
        for (int s = 0; s < 2; ++s)
            *(bf16x8*)&depthT[(cb + 128 * s) * LDT + ks * 32 + hi8] = dv[s];
    }
    __syncthreads();   // depthT ready

    // ---- GEMM2 + in-wave LN: wave w<7 owns out rows 16w..16w+15, all 256 cols ----
    f32x4 acc[16];
    #pragma unroll
    for (int ct = 0; ct < 16; ++ct) acc[ct] = (f32x4){0.f, 0.f, 0.f, 0.f};
    float mu[4], rs[4];

    if (w < 7) {
        const int arow = (w * 16 + ln16 < NN) ? (w * 16 + ln16) : (NN - 1); // rows>=100 discarded
        bf16x8 av[4];
        #pragma unroll
        for (int ks = 0; ks < 4; ++ks)
            av[ks] = *(const bf16x8*)(pwb + arow * 128 + ks * 32 + hi8);
        // pw cols >=100 are uninitialized (could be NaN; NaN*0=NaN) -> zero them;
        // depthT rows >=100 are zero so the masked products contribute nothing.
        #pragma unroll
        for (int j = 0; j < 8; ++j)
            av[3][j] = (96 + hi8 + j < NN) ? av[3][j] : (bf16)0.f;

        #pragma unroll
        for (int ct = 0; ct < 16; ++ct) {
            #pragma unroll
            for (int ks = 0; ks < 4; ++ks) {
                bf16x8 bv = *(const bf16x8*)&depthT[(ct * 16 + ln16) * LDT + ks * 32 + hi8];
                acc[ct] = __builtin_amdgcn_mfma_f32_16x16x32_bf16(av[ks], bv, acc[ct], 0, 0, 0);
            }
        }
        // LN fully in-wave: row n = 16w+g*4+r; (ct, ln16) spans all 256 cols
        #pragma unroll
        for (int r = 0; r < 4; ++r) {
            float s1 = 0.f, s2 = 0.f;
            #pragma unroll
            for (int ct = 0; ct < 16; ++ct) { float a = acc[ct][r]; s1 += a; s2 += a * a; }
            #pragma unroll
            for (int mk = 1; mk < 16; mk <<= 1) {
                s1 += __shfl_xor(s1, mk);
                s2 += __shfl_xor(s2, mk);
            }
            float m_ = s1 * (1.f / 256.f);
            float v_ = s2 * (1.f / 256.f) - m_ * m_;
            mu[r] = m_;
            rs[r] = rsqrtf(fmaxf(v_, 0.f) + 1e-5f);
        }
    }
    __syncthreads();   // all depthT/pw reads done -> OT alias + out overwrite safe

    // ---- normalize + transpose through LDS, two half-passes of 64 rows ----
    #pragma unroll
    for (int h = 0; h < 2; ++h) {
        if (w >= 4 * h && w < 4 * h + 4 && w < 7) {
            const int slot = w - 4 * h;
            #pragma unroll
            for (int ct = 0; ct < 16; ++ct) {
                const float gmv = gamma[ct * 16 + ln16], btv = beta[ct * 16 + ln16];
                #pragma unroll
                for (int r = 0; r < 4; ++r)
                    OT[(slot * 16 + g * 4 + r) * OTS + ct * 16 + ln16] =
                        (acc[ct][r] - mu[r]) * rs[r] * gmv + btv;
            }
        }
        __syncthreads();
        const int rows = h ? 36 : 64;        // h=1: rows 64..99 only
        #pragma unroll
        for (int p = 0; p < 8; ++p) {
            int idx = p * 512 + t;
            if (idx < rows * 64) {
                int row = idx >> 6, c4 = (idx & 63) << 2;
                *(f32x4*)(ob + (size_t)(64 * h + row) * CC + c4) = *(const f32x4*)&OT[row * OTS + c4];
            }
        }
        if (h == 0) __syncthreads();
    }
}

extern "C" void kernel_launch(void* const* d_in, const int* in_sizes, int n_in,
                              void* d_out, int out_size, void* d_ws, size_t ws_size,
                              hipStream_t stream) {
    const float* query = (const float*)d_in[0];
    const float* value = (const float*)d_in[1];
    const float* W     = (const float*)d_in[2];
    const float* bwl   = (const float*)d_in[3];
    const float* gamma = (const float*)d_in[4];
    const float* beta  = (const float*)d_in[5];
    float* out = (float*)d_out;
    bf16* Wt = (bf16*)d_ws;   // 103*256*2 = 52736 B

    wl_transpose<<<dim3((NKK * CC + 255) / 256), dim3(256), 0, stream>>>(W, Wt);
    gemm1<<<dim3(800), dim3(256), 0, stream>>>(query, Wt, bwl, out);
    conv_gemm2_ln<<<dim3(512), dim3(512), 0, stream>>>(value, gamma, beta, out);
}

// Round 10
// 186.076 us; speedup vs baseline: 1.1647x; 1.0010x over previous
//
#include <hip/hip_runtime.h>

#define NN 100
#define CC 256
#define NKK 103
#define LDT 136    // depthT stride (bf16): 272 B rows; must be >= 128 (padded contraction range)
#define OTS 260    // out-transpose stride (f32): 1040 B rows; 1040 % 128 = 16 -> granule walks
                   // per row -> OT writes are perfect 2-way (free). 264 was 4-way (r9: 2.16M conflicts)
#define LDW 136    // gemm1 stage stride (bf16)

typedef __bf16 bf16;
typedef __bf16 bf16x8 __attribute__((ext_vector_type(8)));
typedef float f32x4 __attribute__((ext_vector_type(4)));

// Per-batch scratch carved from the head of the out buffer (f32 units, 25600/batch):
//   [    0, 6400)  pw  bf16 [100][128]   (cols 100..127 junk -> masked in k2)
//   [ 6400, 6800)  dw  f32  [100][4]     (col 3 unused)
// kernel-2 block b reads ONLY batch b's scratch, all before overwriting out[b].

// kernel0: W (f32 [256][103]) -> Wt (bf16 [103][256]) in workspace.
__global__ void wl_transpose(const float* __restrict__ W, bf16* __restrict__ Wt)
{
    int idx = blockIdx.x * 256 + threadIdx.x;
    if (idx < NKK * CC) {
        int ka = idx >> 8;      // /256
        int k  = idx & 255;
        Wt[ka * CC + k] = (bf16)W[k * NKK + ka];
    }
}

// kernel1: dy = q@W + bias as a flat GEMM [51200][256] x [256][103].
// 800 blocks x 256 thr, wave owns a 16-row tile x all 103 cols.
// Epilogue stages the D tile in wave-private LDS then stores pw as coalesced
// 256B row segments (r9's 56 scattered 2B-stores were the suspected gemm1 cost).
__global__ __launch_bounds__(256, 4)
void gemm1(const float* __restrict__ query, const bf16* __restrict__ Wt,
           const float* __restrict__ bwl, float* __restrict__ out)
{
    __shared__ __align__(16) bf16 ST[4][16][LDW];   // 17408 B, wave-private slices
    const int t    = threadIdx.x;
    const int w    = t >> 6;
    const int lane = t & 63;
    const int ln16 = lane & 15;
    const int g    = lane >> 4;
    const int hi8  = g * 8;
    const int R0   = blockIdx.x * 64 + w * 16;     // wave's flat row tile (< 51200)

    // A fragments: row R0+ln16, all 256 k (8 frags; g-groups tile the row)
    const float* qr = query + (size_t)(R0 + ln16) * CC;
    bf16x8 qfr[8];
    #pragma unroll
    for (int f = 0; f < 8; ++f) {
        const int col = f * 32 + hi8;
        f32x4 a0 = *(const f32x4*)(qr + col);
        f32x4 a1 = *(const f32x4*)(qr + col + 4);
        #pragma unroll
        for (int i = 0; i < 4; ++i) { qfr[f][i] = (bf16)a0[i]; qfr[f][i + 4] = (bf16)a1[i]; }
    }

    f32x4 acc[7];
    #pragma unroll
    for (int J = 0; J < 7; ++J) acc[J] = (f32x4){0.f, 0.f, 0.f, 0.f};

    #pragma unroll
    for (int J = 0; J < 7; ++J) {
        const int rB = (J * 16 + ln16 < NKK) ? (J * 16 + ln16) : (NKK - 1); // cols>=103 discarded
        const bf16* wr = Wt + rB * CC;
        #pragma unroll
        for (int f = 0; f < 8; ++f) {
            bf16x8 bv = *(const bf16x8*)(wr + f * 32 + hi8);
            acc[J] = __builtin_amdgcn_mfma_f32_16x16x32_bf16(qfr[f], bv, acc[J], 0, 0, 0);
        }
    }

    // epilogue: stage pw cols (kap in [3,103) -> LDS col kap-3); dw (kap<3) direct
    #pragma unroll
    for (int J = 0; J < 7; ++J) {
        int kap = J * 16 + ln16;
        float bw = (kap < NKK) ? bwl[kap] : 0.f;
        #pragma unroll
        for (int r = 0; r < 4; ++r) {
            float v = acc[J][r] + bw;
            int row = g * 4 + r;
            if (kap >= 3 && kap < NKK) {
                ST[w][row][kap - 3] = (bf16)v;
            } else if (J == 0 && kap < 3) {
                int nf  = R0 + row;
                int bbb = nf / 100, nnr = nf - bbb * 100;
                out[(size_t)bbb * 25600 + 6400 + nnr * 4 + kap] = v;   // dw f32
            }
        }
    }
    // wave-local LDS read-back (compiler inserts lgkmcnt) -> coalesced 256B row stores.
    // LDS cols 100..127 are stale garbage -> written to pw pad cols, masked in k2.
    #pragma unroll
    for (int p = 0; p < 4; ++p) {
        int row = p * 4 + g;                // 0..15
        int nf  = R0 + row;
        int bbb = nf / 100, nnr = nf - bbb * 100;
        bf16x8 vrow = *(const bf16x8*)&ST[w][row][ln16 * 8];
        *(bf16x8*)((bf16*)(out + (size_t)bbb * 25600) + nnr * 128 + ln16 * 8) = vrow;
    }
}

// kernel2: conv -> depthT(LDS) -> GEMM2 -> in-wave LN -> coalesced store.
// 512 blocks x 512 thr (8 waves); 124 unified regs live @128 cap (r9: zero spills);
// 2 blocks/CU, 16 waves/CU.
// SMEM: [0,69632) depthT bf16 [256][136] ; [69632,71232) dw f32 [100][4]
//       store phase: OT f32 [64][260] (66560 B) aliases everything
__global__ __launch_bounds__(512, 4)
void conv_gemm2_ln(const float* __restrict__ value,
                   const float* __restrict__ gamma,
                   const float* __restrict__ beta,
                   float* __restrict__ out)
{
    __shared__ __align__(16) char SMEM[71232];
    bf16* depthT = (bf16*)SMEM;                       // [256][LDT]
    float (*DWs)[4] = (float(*)[4])(SMEM + 69632);    // [100][4]
    float* OT = (float*)SMEM;                         // [64][OTS]

    const int t    = threadIdx.x;
    const int w    = t >> 6;          // wave 0..7
    const int lane = t & 63;
    const int ln16 = lane & 15;
    const int g    = lane >> 4;
    const int hi8  = g * 8;
    const int b    = blockIdx.x;
    const int cb   = w * 16 + ln16;   // channel base 0..127; lane owns cb + 128*s

    float* ob = out + (size_t)b * 25600;
    const bf16*  pwb = (const bf16*)ob;               // [100][128]
    const float* vb  = value + (size_t)b * NN * CC;

    // stage dw -> LDS; prefetch ks=0 value (m<32 always valid)
    if (t < 400) ((float*)DWs)[t] = ob[6400 + t];
    float xv[2][8];
    #pragma unroll
    for (int s = 0; s < 2; ++s)
        #pragma unroll
        for (int j = 0; j < 8; ++j)
            xv[s][j] = vb[(hi8 + j) * CC + cb + 128 * s];
    __syncthreads();   // DWs visible

    // ---- conv: depth[m][c] = relu(dw0*v[m][c-1]+dw1*v[m][c]+dw2*v[m][c+1]) ----
    // stored transposed: depthT[c][m], zero for m in [100,128); [128,136) pad never read
    #pragma unroll
    for (int ks = 0; ks < 4; ++ks) {
        if (ks) {
            #pragma unroll
            for (int s = 0; s < 2; ++s)
                #pragma unroll
                for (int j = 0; j < 8; ++j) {
                    int m = ks * 32 + hi8 + j;
                    xv[s][j] = (m < NN) ? vb[m * CC + cb + 128 * s] : 0.f;
                }
        }
        bf16x8 dv[2];
        #pragma unroll
        for (int j = 0; j < 8; ++j) {
            int  m  = ks * 32 + hi8 + j;
            bool mv = (m < NN);
            int  mc = mv ? m : (NN - 1);
            float w0 = DWs[mc][0], w1 = DWs[mc][1], w2 = DWs[mc][2];
            #pragma unroll
            for (int s = 0; s < 2; ++s) {
                int c = cb + 128 * s;
                float x0 = xv[s][j];
                float xm = __shfl(x0, (lane - 1) & 63);
                float xp = __shfl(x0, (lane + 1) & 63);
                if (ln16 == 0)  xm = (mv && c > 0)      ? vb[m * CC + c - 1] : 0.f;
                if (ln16 == 15) xp = (mv && c + 1 < CC) ? vb[m * CC + c + 1] : 0.f;
                float d = w0 * xm + w1 * x0 + w2 * xp;
                dv[s][j] = (bf16)(mv ? fmaxf(d, 0.f) : 0.f);
            }
        }
        #pragma unroll
        for (int s = 0; s < 2; ++s)
            *(bf16x8*)&depthT[(cb + 128 * s) * LDT + ks * 32 + hi8] = dv[s];
    }

    // issue pw A-fragment loads BEFORE the barrier: latency drains under it
    // (xv is dead here, so no net register-pressure increase)
    bf16x8 av[4];
    if (w < 7) {
        const int arow = (w * 16 + ln16 < NN) ? (w * 16 + ln16) : (NN - 1); // rows>=100 discarded
        #pragma unroll
        for (int ks = 0; ks < 4; ++ks)
            av[ks] = *(const bf16x8*)(pwb + arow * 128 + ks * 32 + hi8);
    }
    __syncthreads();   // depthT ready

    // ---- GEMM2 + in-wave LN: wave w<7 owns out rows 16w..16w+15, all 256 cols ----
    f32x4 acc[16];
    #pragma unroll
    for (int ct = 0; ct < 16; ++ct) acc[ct] = (f32x4){0.f, 0.f, 0.f, 0.f};
    float mu[4], rs[4];

    if (w < 7) {
        // pw cols >=100 are junk (NaN*0=NaN) -> zero them; depthT rows >=100 are 0.
        #pragma unroll
        for (int j = 0; j < 8; ++j)
            av[3][j] = (96 + hi8 + j < NN) ? av[3][j] : (bf16)0.f;

        #pragma unroll
        for (int ct = 0; ct < 16; ++ct) {
            #pragma unroll
            for (int ks = 0; ks < 4; ++ks) {
                bf16x8 bv = *(const bf16x8*)&depthT[(ct * 16 + ln16) * LDT + ks * 32 + hi8];
                acc[ct] = __builtin_amdgcn_mfma_f32_16x16x32_bf16(av[ks], bv, acc[ct], 0, 0, 0);
            }
        }
        // LN fully in-wave: row n = 16w+g*4+r; (ct, ln16) spans all 256 cols
        #pragma unroll
        for (int r = 0; r < 4; ++r) {
            float s1 = 0.f, s2 = 0.f;
            #pragma unroll
            for (int ct = 0; ct < 16; ++ct) { float a = acc[ct][r]; s1 += a; s2 += a * a; }
            #pragma unroll
            for (int mk = 1; mk < 16; mk <<= 1) {
                s1 += __shfl_xor(s1, mk);
                s2 += __shfl_xor(s2, mk);
            }
            float m_ = s1 * (1.f / 256.f);
            float v_ = s2 * (1.f / 256.f) - m_ * m_;
            mu[r] = m_;
            rs[r] = rsqrtf(fmaxf(v_, 0.f) + 1e-5f);
        }
    }
    __syncthreads();   // all depthT/pw reads done -> OT alias + out overwrite safe

    // ---- normalize + transpose through LDS, two half-passes of 64 rows ----
    #pragma unroll
    for (int h = 0; h < 2; ++h) {
        if (w >= 4 * h && w < 4 * h + 4 && w < 7) {
            const int slot = w - 4 * h;
            #pragma unroll
            for (int ct = 0; ct < 16; ++ct) {
                const float gmv = gamma[ct * 16 + ln16], btv = beta[ct * 16 + ln16];
                #pragma unroll
                for (int r = 0; r < 4; ++r)
                    OT[(slot * 16 + g * 4 + r) * OTS + ct * 16 + ln16] =
                        (acc[ct][r] - mu[r]) * rs[r] * gmv + btv;
            }
        }
        __syncthreads();
        const int rows = h ? 36 : 64;        // h=1: rows 64..99 only
        #pragma unroll
        for (int p = 0; p < 8; ++p) {
            int idx = p * 512 + t;
            if (idx < rows * 64) {
                int row = idx >> 6, c4 = (idx & 63) << 2;
                *(f32x4*)(ob + (size_t)(64 * h + row) * CC + c4) = *(const f32x4*)&OT[row * OTS + c4];
            }
        }
        if (h == 0) __syncthreads();
    }
}

extern "C" void kernel_launch(void* const* d_in, const int* in_sizes, int n_in,
                              void* d_out, int out_size, void* d_ws, size_t ws_size,
                              hipStream_t stream) {
    const float* query = (const float*)d_in[0];
    const float* value = (const float*)d_in[1];
    const float* W     = (const float*)d_in[2];
    const float* bwl   = (const float*)d_in[3];
    const float* gamma = (const float*)d_in[4];
    const float* beta  = (const float*)d_in[5];
    float* out = (float*)d_out;
    bf16* Wt = (bf16*)d_ws;   // 103*256*2 = 52736 B

    wl_transpose<<<dim3((NKK * CC + 255) / 256), dim3(256), 0, stream>>>(W, Wt);
    gemm1<<<dim3(800), dim3(256), 0, stream>>>(query, Wt, bwl, out);
    conv_gemm2_ln<<<dim3(512), dim3(512), 0, stream>>>(value, gamma, beta, out);
}

// Round 11
// 173.933 us; speedup vs baseline: 1.2460x; 1.0698x over previous
//
#include <hip/hip_runtime.h>

#define NN 100
#define CC 256
#define NKK 103
#define LDT 136    // depthT stride (bf16): 272 B rows; must be >= 128 (padded contraction range)
#define OTS 260    // out-transpose stride (f32): 1040 B rows; 1040 % 128 = 16 -> 2-way (free)
#define LQS 264    // gemm1 q-stage stride (bf16): 528 B rows; 528 % 128 = 16 -> 2-way (free)

typedef __bf16 bf16;
typedef __bf16 bf16x4 __attribute__((ext_vector_type(4)));
typedef __bf16 bf16x8 __attribute__((ext_vector_type(8)));
typedef float f32x4 __attribute__((ext_vector_type(4)));

// Per-batch scratch carved from the head of the out buffer (f32 units, 25600/batch):
//   [    0, 6400)  pw  bf16 [100][128]   (cols 100..127 junk -> masked in k2)
//   [ 6400, 6800)  dw  f32  [100][4]     (col 3 unused)
// kernel-2 block b reads ONLY batch b's scratch, all before overwriting out[b].

// kernel0: W (f32 [256][103]) -> Wt2 (bf16, FRAGMENT order) in workspace.
// Wt2[((J*8+f)*64 + lane)*8 + j] = W^T[J*16+ln16][f*32+g*8+j]  (lane=(g<<4)|ln16)
// -> gemm1's B-fragment loads become lane-contiguous 1KB streams (4 txns/instr,
//    vs 64 txns/instr for the old row-scattered reads -- r10's txn-rate bottleneck).
__global__ void wl_frag(const float* __restrict__ W, bf16* __restrict__ Wt2)
{
    int idx = blockIdx.x * 256 + threadIdx.x;     // 7*8*64*8 = 28672
    if (idx < 7 * 8 * 64 * 8) {
        int j    = idx & 7;
        int lane = (idx >> 3) & 63;
        int f    = (idx >> 9) & 7;
        int J    = idx >> 12;
        int ka   = J * 16 + (lane & 15);
        if (ka > NKK - 1) ka = NKK - 1;           // clamped cols discarded in epilogue
        int k    = f * 32 + ((lane >> 4) << 3) + j;
        Wt2[idx] = (bf16)W[k * NKK + ka];
    }
}

// kernel1: dy = q@W + bias as a flat GEMM [51200][256] x [256][103].
// 800 blocks x 256 thr. TXN-RATE fix (r10 post-mortem): q staged through LDS with
// coalesced row loads (1KB/instr); W read from fragment-ordered Wt2 (1KB/instr);
// A/B fragments come from ds_read_b128. Epilogue: LDS-staged coalesced pw stores.
__global__ __launch_bounds__(256, 4)
void gemm1(const float* __restrict__ query, const bf16* __restrict__ Wt2,
           const float* __restrict__ bwl, float* __restrict__ out)
{
    __shared__ __align__(16) bf16 ST[4][16][LQS];   // 33792 B; q-stage, then pw-stage
    const int t    = threadIdx.x;
    const int w    = t >> 6;
    const int lane = t & 63;
    const int ln16 = lane & 15;
    const int g    = lane >> 4;
    const int hi8  = g * 8;
    const int R0   = blockIdx.x * 64 + w * 16;     // wave's flat row tile (< 51200)

    // stage q rows R0..R0+15 (wave-local): 16 coalesced 1KB row reads
    const float* qb = query + (size_t)R0 * CC;
    #pragma unroll
    for (int p = 0; p < 16; ++p) {
        f32x4 v = *(const f32x4*)(qb + p * CC + lane * 4);
        bf16x4 s;
        #pragma unroll
        for (int i = 0; i < 4; ++i) s[i] = (bf16)v[i];
        *(bf16x4*)&ST[w][p][lane * 4] = s;
    }
    __syncthreads();   // cross-lane LDS visibility (cheap: one barrier, 4 waves)

    // A fragments from LDS: row ln16, 8 col-frags (2-way banks, free)
    bf16x8 qfr[8];
    #pragma unroll
    for (int f = 0; f < 8; ++f)
        qfr[f] = *(const bf16x8*)&ST[w][ln16][f * 32 + hi8];

    f32x4 acc[7];
    #pragma unroll
    for (int J = 0; J < 7; ++J) acc[J] = (f32x4){0.f, 0.f, 0.f, 0.f};

    #pragma unroll
    for (int J = 0; J < 7; ++J) {
        const bf16* wb = Wt2 + (size_t)(J * 8) * 512 + lane * 8;   // lane-contiguous
        #pragma unroll
        for (int f = 0; f < 8; ++f) {
            bf16x8 bv = *(const bf16x8*)(wb + f * 512);
            acc[J] = __builtin_amdgcn_mfma_f32_16x16x32_bf16(qfr[f], bv, acc[J], 0, 0, 0);
        }
    }
    __syncthreads();   // q-stage reads done -> ST reuse for pw staging

    // epilogue: stage pw cols (kap in [3,103) -> LDS col kap-3); dw (kap<3) direct
    #pragma unroll
    for (int J = 0; J < 7; ++J) {
        int kap = J * 16 + ln16;
        float bw = (kap < NKK) ? bwl[kap] : 0.f;
        #pragma unroll
        for (int r = 0; r < 4; ++r) {
            float v = acc[J][r] + bw;
            int row = g * 4 + r;
            if (kap >= 3 && kap < NKK) {
                ST[w][row][kap - 3] = (bf16)v;
            } else if (J == 0 && kap < 3) {
                int nf  = R0 + row;
                int bbb = nf / 100, nnr = nf - bbb * 100;
                out[(size_t)bbb * 25600 + 6400 + nnr * 4 + kap] = v;   // dw f32
            }
        }
    }
    // wave-local read-back -> coalesced 256B pw row stores.
    // LDS cols 100..127 stale -> written to pw pad cols, masked in k2.
    #pragma unroll
    for (int p = 0; p < 4; ++p) {
        int row = p * 4 + g;                // 0..15
        int nf  = R0 + row;
        int bbb = nf / 100, nnr = nf - bbb * 100;
        bf16x8 vrow = *(const bf16x8*)&ST[w][row][ln16 * 8];
        *(bf16x8*)((bf16*)(out + (size_t)bbb * 25600) + nnr * 128 + ln16 * 8) = vrow;
    }
}

// kernel2: conv -> depthT(LDS) -> GEMM2 -> in-wave LN -> coalesced store.
// 512 blocks x 512 thr (8 waves); 124 unified regs @128 cap (r9/r10: zero spills);
// 2 blocks/CU, 16 waves/CU.  r11 change: DWs stride 4->5 f32 (g-groups 8 rows
// apart hit bank +8 instead of the same bank -- r10's residual 1.7M conflicts).
// SMEM: [0,69632) depthT bf16 [256][136] ; [69632,71632) dw f32 [100][5]
//       store phase: OT f32 [64][260] (66560 B) aliases depthT
__global__ __launch_bounds__(512, 4)
void conv_gemm2_ln(const float* __restrict__ value,
                   const float* __restrict__ gamma,
                   const float* __restrict__ beta,
                   float* __restrict__ out)
{
    __shared__ __align__(16) char SMEM[71632];
    bf16* depthT = (bf16*)SMEM;                       // [256][LDT]
    float (*DWs)[5] = (float(*)[5])(SMEM + 69632);    // [100][5], col 4 pad
    float* OT = (float*)SMEM;                         // [64][OTS]

    const int t    = threadIdx.x;
    const int w    = t >> 6;          // wave 0..7
    const int lane = t & 63;
    const int ln16 = lane & 15;
    const int g    = lane >> 4;
    const int hi8  = g * 8;
    const int b    = blockIdx.x;
    const int cb   = w * 16 + ln16;   // channel base 0..127; lane owns cb + 128*s

    float* ob = out + (size_t)b * 25600;
    const bf16*  pwb = (const bf16*)ob;               // [100][128]
    const float* vb  = value + (size_t)b * NN * CC;

    // stage dw -> LDS ([100][4] global -> [100][5] padded); prefetch ks=0 value
    if (t < 400) DWs[t >> 2][t & 3] = ob[6400 + t];
    float xv[2][8];
    #pragma unroll
    for (int s = 0; s < 2; ++s)
        #pragma unroll
        for (int j = 0; j < 8; ++j)
            xv[s][j] = vb[(hi8 + j) * CC + cb + 128 * s];
    __syncthreads();   // DWs visible

    // ---- conv: depth[m][c] = relu(dw0*v[m][c-1]+dw1*v[m][c]+dw2*v[m][c+1]) ----
    // stored transposed: depthT[c][m], zero for m in [100,128); [128,136) pad never read
    #pragma unroll
    for (int ks = 0; ks < 4; ++ks) {
        if (ks) {
            #pragma unroll
            for (int s = 0; s < 2; ++s)
                #pragma unroll
                for (int j = 0; j < 8; ++j) {
                    int m = ks * 32 + hi8 + j;
                    xv[s][j] = (m < NN) ? vb[m * CC + cb + 128 * s] : 0.f;
                }
        }
        bf16x8 dv[2];
        #pragma unroll
        for (int j = 0; j < 8; ++j) {
            int  m  = ks * 32 + hi8 + j;
            bool mv = (m < NN);
            int  mc = mv ? m : (NN - 1);
            float w0 = DWs[mc][0], w1 = DWs[mc][1], w2 = DWs[mc][2];
            #pragma unroll
            for (int s = 0; s < 2; ++s) {
                int c = cb + 128 * s;
                float x0 = xv[s][j];
                float xm = __shfl(x0, (lane - 1) & 63);
                float xp = __shfl(x0, (lane + 1) & 63);
                if (ln16 == 0)  xm = (mv && c > 0)      ? vb[m * CC + c - 1] : 0.f;
                if (ln16 == 15) xp = (mv && c + 1 < CC) ? vb[m * CC + c + 1] : 0.f;
                float d = w0 * xm + w1 * x0 + w2 * xp;
                dv[s][j] = (bf16)(mv ? fmaxf(d, 0.f) : 0.f);
            }
        }
        #pragma unroll
        for (int s = 0; s < 2; ++s)
            *(bf16x8*)&depthT[(cb + 128 * s) * LDT + ks * 32 + hi8] = dv[s];
    }

    // issue pw A-fragment loads BEFORE the barrier: latency drains under it
    bf16x8 av[4];
    if (w < 7) {
        const int arow = (w * 16 + ln16 < NN) ? (w * 16 + ln16) : (NN - 1); // rows>=100 discarded
        #pragma unroll
        for (int ks = 0; ks < 4; ++ks)
            av[ks] = *(const bf16x8*)(pwb + arow * 128 + ks * 32 + hi8);
    }
    __syncthreads();   // depthT ready

    // ---- GEMM2 + in-wave LN: wave w<7 owns out rows 16w..16w+15, all 256 cols ----
    f32x4 acc[16];
    #pragma unroll
    for (int ct = 0; ct < 16; ++ct) acc[ct] = (f32x4){0.f, 0.f, 0.f, 0.f};
    float mu[4], rs[4];

    if (w < 7) {
        // pw cols >=100 are junk (NaN*0=NaN) -> zero them; depthT rows >=100 are 0.
        #pragma unroll
        for (int j = 0; j < 8; ++j)
            av[3][j] = (96 + hi8 + j < NN) ? av[3][j] : (bf16)0.f;

        #pragma unroll
        for (int ct = 0; ct < 16; ++ct) {
            #pragma unroll
            for (int ks = 0; ks < 4; ++ks) {
                bf16x8 bv = *(const bf16x8*)&depthT[(ct * 16 + ln16) * LDT + ks * 32 + hi8];
                acc[ct] = __builtin_amdgcn_mfma_f32_16x16x32_bf16(av[ks], bv, acc[ct], 0, 0, 0);
            }
        }
        // LN fully in-wave: row n = 16w+g*4+r; (ct, ln16) spans all 256 cols
        #pragma unroll
        for (int r = 0; r < 4; ++r) {
            float s1 = 0.f, s2 = 0.f;
            #pragma unroll
            for (int ct = 0; ct < 16; ++ct) { float a = acc[ct][r]; s1 += a; s2 += a * a; }
            #pragma unroll
            for (int mk = 1; mk < 16; mk <<= 1) {
                s1 += __shfl_xor(s1, mk);
                s2 += __shfl_xor(s2, mk);
            }
            float m_ = s1 * (1.f / 256.f);
            float v_ = s2 * (1.f / 256.f) - m_ * m_;
            mu[r] = m_;
            rs[r] = rsqrtf(fmaxf(v_, 0.f) + 1e-5f);
        }
    }
    __syncthreads();   // all depthT/pw reads done -> OT alias + out overwrite safe

    // ---- normalize + transpose through LDS, two half-passes of 64 rows ----
    #pragma unroll
    for (int h = 0; h < 2; ++h) {
        if (w >= 4 * h && w < 4 * h + 4 && w < 7) {
            const int slot = w - 4 * h;
            #pragma unroll
            for (int ct = 0; ct < 16; ++ct) {
                const float gmv = gamma[ct * 16 + ln16], btv = beta[ct * 16 + ln16];
                #pragma unroll
                for (int r = 0; r < 4; ++r)
                    OT[(slot * 16 + g * 4 + r) * OTS + ct * 16 + ln16] =
                        (acc[ct][r] - mu[r]) * rs[r] * gmv + btv;
            }
        }
        __syncthreads();
        const int rows = h ? 36 : 64;        // h=1: rows 64..99 only
        #pragma unroll
        for (int p = 0; p < 8; ++p) {
            int idx = p * 512 + t;
            if (idx < rows * 64) {
                int row = idx >> 6, c4 = (idx & 63) << 2;
                *(f32x4*)(ob + (size_t)(64 * h + row) * CC + c4) = *(const f32x4*)&OT[row * OTS + c4];
            }
        }
        if (h == 0) __syncthreads();
    }
}

extern "C" void kernel_launch(void* const* d_in, const int* in_sizes, int n_in,
                              void* d_out, int out_size, void* d_ws, size_t ws_size,
                              hipStream_t stream) {
    const float* query = (const float*)d_in[0];
    const float* value = (const float*)d_in[1];
    const float* W     = (const float*)d_in[2];
    const float* bwl   = (const float*)d_in[3];
    const float* gamma = (const float*)d_in[4];
    const float* beta  = (const float*)d_in[5];
    float* out = (float*)d_out;
    bf16* Wt2 = (bf16*)d_ws;   // 7*8*64*8*2 = 57344 B fragment-ordered W

    wl_frag<<<dim3(112), dim3(256), 0, stream>>>(W, Wt2);
    gemm1<<<dim3(800), dim3(256), 0, stream>>>(query, Wt2, bwl, out);
    conv_gemm2_ln<<<dim3(512), dim3(512), 0, stream>>>(value, gamma, beta, out);
}